// Round 3
// baseline (1483.937 us; speedup 1.0000x reference)
//
#include <hip/hip_runtime.h>
#include <math.h>

#define B_ 128
#define L_ 512
#define D_ 512
#define E_ 64
#define H_ 512
#define V_ 17

#define LOG2E_F 1.4426950408889634f
#define LN2_F   0.6931471805599453f

__device__ __forceinline__ float fast_tanh(float x) {
  // tanh(x) = 1 - 2/(1+e^{2x}); saturates correctly via exp2 over/underflow
  float e = __builtin_amdgcn_exp2f(x * (2.0f * LOG2E_F));
  return 1.0f - 2.0f * __builtin_amdgcn_rcpf(e + 1.0f);
}

// ---------------- DH precompute: DH[v][h] = sum_e W1[h][D+e] * table[v][e], row 0 zeroed
__global__ void dh_kernel(const float* __restrict__ W1, const float* __restrict__ table,
                          float* __restrict__ DH) {
  int h = threadIdx.x; // 512 threads
  float w[E_];
#pragma unroll
  for (int e = 0; e < E_; ++e) w[e] = W1[h * (D_ + E_) + D_ + e];
  DH[h] = 0.f; // v = 0 (PAD row is zero)
  for (int v = 1; v < V_; ++v) {
    float acc = 0.f;
#pragma unroll
    for (int e = 0; e < E_; ++e) acc += w[e] * table[v * E_ + e];
    DH[v * H_ + h] = acc;
  }
}

// ---------------- fp32 GEMM: Z[m][n] = sum_k A[m][k] * W1[n][k] + b1[n]
#define BM 128
#define BN 128
#define BK 16
#define LDS_S 132

__global__ __launch_bounds__(256)
void gemm_kernel(const float* __restrict__ A, const float* __restrict__ W1,
                 const float* __restrict__ b1, float* __restrict__ Z) {
  __shared__ float As[BK * LDS_S];
  __shared__ float Bs[BK * LDS_S];
  const int t = threadIdx.x;
  const int mBase = blockIdx.x * BM;
  const int nBase = blockIdx.y * BN;
  const int tx = t & 15, ty = t >> 4;

  float acc[2][2][4][4];
#pragma unroll
  for (int a = 0; a < 2; a++)
#pragma unroll
    for (int b = 0; b < 2; b++)
#pragma unroll
      for (int i = 0; i < 4; i++)
#pragma unroll
        for (int j = 0; j < 4; j++) acc[a][b][i][j] = 0.f;

  const int rowA0 = t >> 2;
  const int kq = t & 3;

  for (int kt = 0; kt < D_; kt += BK) {
#pragma unroll
    for (int q = 0; q < 2; ++q) {
      const int row = q * 64 + rowA0;
      const float4 av = *(const float4*)&A[(size_t)(mBase + row) * D_ + kt + kq * 4];
      const float4 bv = *(const float4*)&W1[(size_t)(nBase + row) * (D_ + E_) + kt + kq * 4];
#pragma unroll
      for (int i = 0; i < 4; ++i) As[(kq * 4 + i) * LDS_S + row] = ((const float*)&av)[i];
#pragma unroll
      for (int i = 0; i < 4; ++i) Bs[(kq * 4 + i) * LDS_S + row] = ((const float*)&bv)[i];
    }
    __syncthreads();
#pragma unroll
    for (int k = 0; k < BK; ++k) {
      float4 a0 = *(const float4*)&As[k * LDS_S + ty * 4];
      float4 a1 = *(const float4*)&As[k * LDS_S + ty * 4 + 64];
      float4 b0 = *(const float4*)&Bs[k * LDS_S + tx * 4];
      float4 b1v = *(const float4*)&Bs[k * LDS_S + tx * 4 + 64];
      float am[2][4] = {{a0.x, a0.y, a0.z, a0.w}, {a1.x, a1.y, a1.z, a1.w}};
      float bn[2][4] = {{b0.x, b0.y, b0.z, b0.w}, {b1v.x, b1v.y, b1v.z, b1v.w}};
#pragma unroll
      for (int am_ = 0; am_ < 2; am_++)
#pragma unroll
        for (int bn_ = 0; bn_ < 2; bn_++)
#pragma unroll
          for (int i = 0; i < 4; i++)
#pragma unroll
            for (int j = 0; j < 4; j++) acc[am_][bn_][i][j] += am[am_][i] * bn[bn_][j];
    }
    __syncthreads();
  }
#pragma unroll
  for (int bn_ = 0; bn_ < 2; ++bn_) {
    const int n0 = nBase + tx * 4 + bn_ * 64;
    const float4 bias = *(const float4*)&b1[n0];
#pragma unroll
    for (int am_ = 0; am_ < 2; ++am_) {
#pragma unroll
      for (int i = 0; i < 4; i++) {
        const int m = mBase + ty * 4 + am_ * 64 + i;
        float4 o;
        o.x = acc[am_][bn_][i][0] + bias.x;
        o.y = acc[am_][bn_][i][1] + bias.y;
        o.z = acc[am_][bn_][i][2] + bias.z;
        o.w = acc[am_][bn_][i][3] + bias.w;
        *(float4*)&Z[(size_t)m * H_ + n0] = o;
      }
    }
  }
}

// ---------------- candidate transitions: next[b,t][p] = argmax_v logits(z_t, DH[p])
// One wave per (b,t); loop over the 17 candidate p's. Fully parallel over 65536 waves.
#define SPITCH 68

__global__ __launch_bounds__(256, 2)
void cand_kernel(const float* __restrict__ Z, const float* __restrict__ DH,
                 const float* __restrict__ W2, const float* __restrict__ b2,
                 unsigned char* __restrict__ next_g) {
  __shared__ float sDH[V_ * H_];          // 34 KB shared by 4 waves
  __shared__ float sP[4][V_ * SPITCH];    // per-wave partial-logit transpose

  const int tid = threadIdx.x;
  const int w = tid >> 6, ln = tid & 63;
  const int gw = blockIdx.x * 4 + w;      // gw = b*L + t

  for (int i = tid * 4; i < V_ * H_; i += 1024)
    *(float4*)&sDH[i] = *(const float4*)&DH[i];

  float w2a[V_][4], w2b[V_][4];
#pragma unroll
  for (int v = 0; v < V_; ++v) {
    *(float4*)w2a[v] = *(const float4*)&W2[v * H_ + 4 * ln];
    *(float4*)w2b[v] = *(const float4*)&W2[v * H_ + 256 + 4 * ln];
  }
  const float b2r = (ln < V_) ? b2[ln] : 0.f;

  const float* zrow = Z + (size_t)gw * H_;
  const float4 za = *(const float4*)&zrow[4 * ln];
  const float4 zb = *(const float4*)&zrow[256 + 4 * ln];

  __syncthreads();

  float* sp = sP[w];

#pragma unroll 1
  for (int p = 0; p < V_; ++p) {
    const float4 da = *(const float4*)&sDH[p * H_ + 4 * ln];
    const float4 db = *(const float4*)&sDH[p * H_ + 256 + 4 * ln];
    float4 ha, hb;
    ha.x = fast_tanh(za.x + da.x); ha.y = fast_tanh(za.y + da.y);
    ha.z = fast_tanh(za.z + da.z); ha.w = fast_tanh(za.w + da.w);
    hb.x = fast_tanh(zb.x + db.x); hb.y = fast_tanh(zb.y + db.y);
    hb.z = fast_tanh(zb.z + db.z); hb.w = fast_tanh(zb.w + db.w);
    float pv[V_];
#pragma unroll
    for (int v = 0; v < V_; ++v) {
      pv[v] = w2a[v][0] * ha.x + w2a[v][1] * ha.y + w2a[v][2] * ha.z + w2a[v][3] * ha.w
            + w2b[v][0] * hb.x + w2b[v][1] * hb.y + w2b[v][2] * hb.z + w2b[v][3] * hb.w;
    }
#pragma unroll
    for (int v = 0; v < V_; ++v) sp[v * SPITCH + ln] = pv[v];
    // in-order DS pipe within a wave: reads below see the writes above
    float lv = -INFINITY;
    if (ln < V_) {
      const float4* row = (const float4*)&sp[ln * SPITCH];
      float s0 = 0.f, s1 = 0.f, s2 = 0.f, s3 = 0.f;
#pragma unroll
      for (int i = 0; i < 16; ++i) {
        const float4 q = row[i];
        s0 += q.x; s1 += q.y; s2 += q.z; s3 += q.w;
      }
      lv = (s0 + s1) + (s2 + s3) + b2r;
    }
    float m = lv;
#pragma unroll
    for (int off = 16; off >= 1; off >>= 1) m = fmaxf(m, __shfl_xor(m, off, 32));
    int idx = (lv == m) ? ln : 0x7fffffff; // first-max, matches jnp.argmax
#pragma unroll
    for (int off = 16; off >= 1; off >>= 1) idx = min(idx, __shfl_xor(idx, off, 32));
    if (ln == 0) next_g[(size_t)gw * 32 + p] = (unsigned char)idx;
  }
}

// ---------------- serial table walk: pred_t = next[b,t][pred_{t-1}], pred_{-1}=0
__global__ __launch_bounds__(64, 1)
void walk_kernel(const unsigned char* __restrict__ next_g,
                 unsigned char* __restrict__ seq_g,
                 float* __restrict__ out_preds) {
  __shared__ unsigned char sNext[L_ * 32]; // 16 KB
  __shared__ unsigned char sSeq[L_];
  const int b = blockIdx.x, ln = threadIdx.x;
  const uint4* src = (const uint4*)(next_g + (size_t)b * L_ * 32);
  uint4* dst = (uint4*)sNext;
  for (int i = ln; i < L_ * 32 / 16; i += 64) dst[i] = src[i];
  __syncthreads();
  if (ln == 0) {
    int pred = 0;
    for (int t = 0; t < L_; ++t) {
      pred = sNext[t * 32 + pred];
      sSeq[t] = (unsigned char)pred;
    }
  }
  __syncthreads();
  for (int t = ln; t < L_; t += 64) {
    const int pv = sSeq[t];
    out_preds[(size_t)b * L_ + t] = (float)pv;
    seq_g[(size_t)b * L_ + t] = (unsigned char)pv;
  }
}

// ---------------- outputs: recompute logits for the chosen pred, softmax, pemb
__global__ __launch_bounds__(256, 2)
void out_kernel(const float* __restrict__ Z, const float* __restrict__ DH,
                const float* __restrict__ W2, const float* __restrict__ b2,
                const float* __restrict__ table,
                const unsigned char* __restrict__ seq_g,
                float* __restrict__ out_logits, float* __restrict__ out_probs,
                float* __restrict__ out_pemb) {
  __shared__ float sDH[V_ * H_];
  __shared__ float sTab[V_ * E_];
  __shared__ float sP[4][V_ * SPITCH];

  const int tid = threadIdx.x;
  const int w = tid >> 6, ln = tid & 63;
  const int gw = blockIdx.x * 4 + w;      // gw = b*L + t
  const int t = gw & (L_ - 1);

  for (int i = tid * 4; i < V_ * H_; i += 1024)
    *(float4*)&sDH[i] = *(const float4*)&DH[i];
  for (int i = tid * 4; i < V_ * E_; i += 1024) {
    float4 tv = *(const float4*)&table[i];
    if (i < E_) { tv.x = 0.f; tv.y = 0.f; tv.z = 0.f; tv.w = 0.f; } // PAD row
    *(float4*)&sTab[i] = tv;
  }

  float w2a[V_][4], w2b[V_][4];
#pragma unroll
  for (int v = 0; v < V_; ++v) {
    *(float4*)w2a[v] = *(const float4*)&W2[v * H_ + 4 * ln];
    *(float4*)w2b[v] = *(const float4*)&W2[v * H_ + 256 + 4 * ln];
  }
  const float b2r = (ln < V_) ? b2[ln] : 0.f;

  const float* zrow = Z + (size_t)gw * H_;
  const float4 za = *(const float4*)&zrow[4 * ln];
  const float4 zb = *(const float4*)&zrow[256 + 4 * ln];
  const int pprev = (t > 0) ? (int)seq_g[gw - 1] : 0;
  const int pcur = (int)seq_g[gw];

  __syncthreads();

  const float4 da = *(const float4*)&sDH[pprev * H_ + 4 * ln];
  const float4 db = *(const float4*)&sDH[pprev * H_ + 256 + 4 * ln];
  float4 ha, hb;
  ha.x = fast_tanh(za.x + da.x); ha.y = fast_tanh(za.y + da.y);
  ha.z = fast_tanh(za.z + da.z); ha.w = fast_tanh(za.w + da.w);
  hb.x = fast_tanh(zb.x + db.x); hb.y = fast_tanh(zb.y + db.y);
  hb.z = fast_tanh(zb.z + db.z); hb.w = fast_tanh(zb.w + db.w);
  float pv[V_];
#pragma unroll
  for (int v = 0; v < V_; ++v) {
    pv[v] = w2a[v][0] * ha.x + w2a[v][1] * ha.y + w2a[v][2] * ha.z + w2a[v][3] * ha.w
          + w2b[v][0] * hb.x + w2b[v][1] * hb.y + w2b[v][2] * hb.z + w2b[v][3] * hb.w;
  }
  float* sp = sP[w];
#pragma unroll
  for (int v = 0; v < V_; ++v) sp[v * SPITCH + ln] = pv[v];
  float lv = -INFINITY;
  if (ln < V_) {
    const float4* row = (const float4*)&sp[ln * SPITCH];
    float s0 = 0.f, s1 = 0.f, s2 = 0.f, s3 = 0.f;
#pragma unroll
    for (int i = 0; i < 16; ++i) {
      const float4 q = row[i];
      s0 += q.x; s1 += q.y; s2 += q.z; s3 += q.w;
    }
    lv = (s0 + s1) + (s2 + s3) + b2r;
  }
  float m = lv;
#pragma unroll
  for (int off = 16; off >= 1; off >>= 1) m = fmaxf(m, __shfl_xor(m, off, 32));
  const float e = (ln < V_) ? __builtin_amdgcn_exp2f((lv - m) * LOG2E_F) : 0.f;
  float ssum = e;
#pragma unroll
  for (int off = 16; off >= 1; off >>= 1) ssum += __shfl_xor(ssum, off, 32);
  const float lse = __builtin_amdgcn_logf(ssum) * LN2_F;
  if (ln < V_) {
    out_logits[(size_t)gw * V_ + ln] = lv;
    out_probs[(size_t)gw * V_ + ln] = lv - m - lse;
  }
  if (ln < 16) {
    const float4 ev = *(const float4*)&sTab[pcur * E_ + 4 * ln];
    *(float4*)&out_pemb[(size_t)gw * E_ + 4 * ln] = ev;
  }
}

extern "C" void kernel_launch(void* const* d_in, const int* in_sizes, int n_in,
                              void* d_out, int out_size, void* d_ws, size_t ws_size,
                              hipStream_t stream) {
  const float* inputs = (const float*)d_in[0];
  const float* table  = (const float*)d_in[1];
  const float* W1     = (const float*)d_in[2];
  const float* b1     = (const float*)d_in[3];
  const float* W2     = (const float*)d_in[4];
  const float* b2     = (const float*)d_in[5];

  float* out = (float*)d_out;
  float* out_logits = out;                                  // [B,L,V]
  float* out_preds  = out_logits + (size_t)B_ * L_ * V_;    // [B,L]
  float* out_probs  = out_preds + (size_t)B_ * L_;          // [B,L,V]
  float* out_pemb   = out_probs + (size_t)B_ * L_ * V_;     // [B,L,E]

  char* ws = (char*)d_ws;
  float* DH = (float*)ws;                                   // 34 KB (reserve 64 KB)
  float* Z  = (float*)(ws + 65536);                         // 128 MB
  unsigned char* next_g = (unsigned char*)(ws + 65536 + (size_t)134217728);      // 2 MB
  unsigned char* seq_g  = next_g + (size_t)B_ * L_ * 32;                          // 64 KB

  dh_kernel<<<1, 512, 0, stream>>>(W1, table, DH);
  dim3 g(65536 / BM, H_ / BN); // 512 x 4
  gemm_kernel<<<g, 256, 0, stream>>>(inputs, W1, b1, Z);
  cand_kernel<<<B_ * L_ / 4, 256, 0, stream>>>(Z, DH, W2, b2, next_g);
  walk_kernel<<<B_, 64, 0, stream>>>(next_g, seq_g, out_preds);
  out_kernel<<<B_ * L_ / 4, 256, 0, stream>>>(Z, DH, W2, b2, table, seq_g,
                                              out_logits, out_probs, out_pemb);
}

// Round 4
// 932.868 us; speedup vs baseline: 1.5907x; 1.5907x over previous
//
#include <hip/hip_runtime.h>
#include <math.h>

#define B_ 128
#define L_ 512
#define D_ 512
#define E_ 64
#define H_ 512
#define V_ 17

#define LOG2E_F 1.4426950408889634f
#define LN2_F   0.6931471805599453f

__device__ __forceinline__ float fast_tanh(float x) {
  // tanh(x) = 1 - 2/(1+e^{2x}); saturates correctly via exp2 over/underflow
  float e = __builtin_amdgcn_exp2f(x * (2.0f * LOG2E_F));
  return 1.0f - 2.0f * __builtin_amdgcn_rcpf(e + 1.0f);
}

// ---------------- DH precompute: DH[v][h] = sum_e W1[h][D+e] * table[v][e], row 0 zeroed
__global__ void dh_kernel(const float* __restrict__ W1, const float* __restrict__ table,
                          float* __restrict__ DH) {
  int h = threadIdx.x; // 512 threads
  float w[E_];
#pragma unroll
  for (int e = 0; e < E_; ++e) w[e] = W1[h * (D_ + E_) + D_ + e];
  DH[h] = 0.f; // v = 0 (PAD row is zero)
  for (int v = 1; v < V_; ++v) {
    float acc = 0.f;
#pragma unroll
    for (int e = 0; e < E_; ++e) acc += w[e] * table[v * E_ + e];
    DH[v * H_ + h] = acc;
  }
}

// ---------------- split-fp16 3xMFMA GEMM: Z = A * W^T + b1
// A [65536 x 512] fp32, W rows length 576 (use k<512). Each fp32 operand is
// pre-scaled (A*1024, W*256 -> lo-parts stay fp16-normal) and split a=ah+al
// (fp16, 11-bit mantissa x2 = 22 bits); products ah*bh + ah*bl + al*bh leave
// only the 2^-22-relative al*bl term dropped => z error ~ fp32 accum noise.
// Epilogue rescales by 2^-18 exactly and adds b1.
#define GBM 128
#define GBN 128
#define GBK 32
#define PITCH 20          // dwords per row: 16 data + 4 pad (16B aligned, 2-way banks = free)
#define SCALE_A 1024.0f
#define SCALE_W 256.0f
#define INV_SCALE (1.0f / (1024.0f * 256.0f))

typedef _Float16 half8 __attribute__((ext_vector_type(8)));
typedef float float4v __attribute__((ext_vector_type(4)));

__device__ __forceinline__ uint4 split4(float4 v, float scale) {
  // 4 fp32 -> 2 packed-hi dwords + 2 packed-lo dwords (fp16 pairs, elem k in
  // low half of dword k/2)
  float a0 = v.x * scale, a1 = v.y * scale, a2 = v.z * scale, a3 = v.w * scale;
  _Float16 h0 = (_Float16)a0, h1 = (_Float16)a1, h2 = (_Float16)a2, h3 = (_Float16)a3;
  _Float16 l0 = (_Float16)(a0 - (float)h0), l1 = (_Float16)(a1 - (float)h1);
  _Float16 l2 = (_Float16)(a2 - (float)h2), l3 = (_Float16)(a3 - (float)h3);
  union { _Float16 h; unsigned short u; } c;
  unsigned int hu0, hu1, hu2, hu3, lu0, lu1, lu2, lu3;
  c.h = h0; hu0 = c.u; c.h = h1; hu1 = c.u; c.h = h2; hu2 = c.u; c.h = h3; hu3 = c.u;
  c.h = l0; lu0 = c.u; c.h = l1; lu1 = c.u; c.h = l2; lu2 = c.u; c.h = l3; lu3 = c.u;
  uint4 r;
  r.x = hu0 | (hu1 << 16);  // hi elems 0,1
  r.y = hu2 | (hu3 << 16);  // hi elems 2,3
  r.z = lu0 | (lu1 << 16);  // lo elems 0,1
  r.w = lu2 | (lu3 << 16);  // lo elems 2,3
  return r;
}

__global__ __launch_bounds__(256, 2)
void gemm_kernel(const float* __restrict__ A, const float* __restrict__ W1,
                 const float* __restrict__ b1, float* __restrict__ Z) {
  __shared__ unsigned int Ahi[GBM * PITCH], Alo[GBM * PITCH];
  __shared__ unsigned int Whi[GBN * PITCH], Wlo[GBN * PITCH];

  const int t = threadIdx.x;
  const int ln = t & 63, w = t >> 6;
  const int wm = w & 1, wn = w >> 1;          // wave quadrant (64m x 64n)
  const int mBase = blockIdx.x * GBM;
  const int nBase = blockIdx.y * GBN;
  const int lrow = ln & 15, lquad = ln >> 4;  // frag: m/n = lrow, k = lquad*8+j

  float4v acc[4][4];
#pragma unroll
  for (int i = 0; i < 4; ++i)
#pragma unroll
    for (int j = 0; j < 4; ++j) acc[i][j] = (float4v){0.f, 0.f, 0.f, 0.f};

  for (int kt = 0; kt < D_; kt += GBK) {
#pragma unroll
    for (int q = 0; q < 4; ++q) {
      const int idx = q * 256 + t;
      const int m = idx >> 3, f = idx & 7;   // row m, float4-index f (k = 4f)
      const float4 av = *(const float4*)&A[(size_t)(mBase + m) * D_ + kt + 4 * f];
      const uint4 pa = split4(av, SCALE_A);
      *(uint2*)&Ahi[m * PITCH + 2 * f] = make_uint2(pa.x, pa.y);
      *(uint2*)&Alo[m * PITCH + 2 * f] = make_uint2(pa.z, pa.w);
      const float4 wv = *(const float4*)&W1[(size_t)(nBase + m) * (D_ + E_) + kt + 4 * f];
      const uint4 pw = split4(wv, SCALE_W);
      *(uint2*)&Whi[m * PITCH + 2 * f] = make_uint2(pw.x, pw.y);
      *(uint2*)&Wlo[m * PITCH + 2 * f] = make_uint2(pw.z, pw.w);
    }
    __syncthreads();

    half8 ah[4], al[4], bh[4], bl[4];
#pragma unroll
    for (int tm = 0; tm < 4; ++tm) {
      const int off = (wm * 64 + tm * 16 + lrow) * PITCH + 4 * lquad;
      ah[tm] = *(const half8*)&Ahi[off];
      al[tm] = *(const half8*)&Alo[off];
    }
#pragma unroll
    for (int tn = 0; tn < 4; ++tn) {
      const int off = (wn * 64 + tn * 16 + lrow) * PITCH + 4 * lquad;
      bh[tn] = *(const half8*)&Whi[off];
      bl[tn] = *(const half8*)&Wlo[off];
    }
#pragma unroll
    for (int tm = 0; tm < 4; ++tm)
#pragma unroll
      for (int tn = 0; tn < 4; ++tn) {
        acc[tm][tn] = __builtin_amdgcn_mfma_f32_16x16x32_f16(ah[tm], bh[tn], acc[tm][tn], 0, 0, 0);
        acc[tm][tn] = __builtin_amdgcn_mfma_f32_16x16x32_f16(ah[tm], bl[tn], acc[tm][tn], 0, 0, 0);
        acc[tm][tn] = __builtin_amdgcn_mfma_f32_16x16x32_f16(al[tm], bh[tn], acc[tm][tn], 0, 0, 0);
      }
    __syncthreads();
  }

  // epilogue: C[row = lquad*4 + r][col = lrow] per 16x16 tile
#pragma unroll
  for (int tn = 0; tn < 4; ++tn) {
    const int col = nBase + wn * 64 + tn * 16 + lrow;
    const float bv = b1[col];
#pragma unroll
    for (int tm = 0; tm < 4; ++tm) {
      const int row0 = mBase + wm * 64 + tm * 16 + lquad * 4;
#pragma unroll
      for (int r = 0; r < 4; ++r)
        Z[(size_t)(row0 + r) * H_ + col] = acc[tm][tn][r] * INV_SCALE + bv;
    }
  }
}

// ---------------- sequential phase: ONE WAVE per batch row (R2 version).
// No s_barrier anywhere: intra-wave LDS ordering via lgkmcnt; no vmcnt drains,
// so the 2-step-ahead Z prefetch (~1400cy cover vs ~900cy HBM latency) and the
// global stores stay in flight across steps.
#define SP_PITCH 68  // 64 + 4 pad

__global__ __launch_bounds__(64, 1)
void seq_kernel(const float* __restrict__ Z, const float* __restrict__ DH,
                const float* __restrict__ W2, const float* __restrict__ b2,
                const float* __restrict__ table,
                float* __restrict__ out_logits, float* __restrict__ out_preds,
                float* __restrict__ out_probs, float* __restrict__ out_pemb) {
  __shared__ float sDH[V_ * H_];        // 34 KB
  __shared__ float sTab[V_ * E_];       // 4.25 KB
  __shared__ float sP[V_ * SP_PITCH];   // 4.5 KB partial-logit transpose

  const int b = blockIdx.x;
  const int ln = threadIdx.x; // 0..63

  for (int i = ln * 4; i < V_ * H_; i += 256)
    *(float4*)&sDH[i] = *(const float4*)&DH[i];
  for (int i = ln * 4; i < V_ * E_; i += 256) {
    float4 tv = *(const float4*)&table[i];
    if (i < E_) { tv.x = 0.f; tv.y = 0.f; tv.z = 0.f; tv.w = 0.f; } // PAD row
    *(float4*)&sTab[i] = tv;
  }

  float w2a[V_][4], w2b[V_][4];
#pragma unroll
  for (int v = 0; v < V_; ++v) {
    *(float4*)w2a[v] = *(const float4*)&W2[v * H_ + 4 * ln];
    *(float4*)w2b[v] = *(const float4*)&W2[v * H_ + 256 + 4 * ln];
  }
  const float b2r = (ln < V_) ? b2[ln] : 0.f;

  const float* Zb = Z + (size_t)b * L_ * H_;
  float4 za0 = *(const float4*)&Zb[4 * ln];
  float4 zb0 = *(const float4*)&Zb[256 + 4 * ln];
  float4 za1 = *(const float4*)&Zb[(size_t)H_ + 4 * ln];
  float4 zb1 = *(const float4*)&Zb[(size_t)H_ + 256 + 4 * ln];

  int pred = 0;

  auto step = [&](int t, float4& za, float4& zb) {
    const float* dhrow = &sDH[pred * H_];
    const float4 da = *(const float4*)&dhrow[4 * ln];
    const float4 db = *(const float4*)&dhrow[256 + 4 * ln];
    float4 ha, hb;
    ha.x = fast_tanh(za.x + da.x); ha.y = fast_tanh(za.y + da.y);
    ha.z = fast_tanh(za.z + da.z); ha.w = fast_tanh(za.w + da.w);
    hb.x = fast_tanh(zb.x + db.x); hb.y = fast_tanh(zb.y + db.y);
    hb.z = fast_tanh(zb.z + db.z); hb.w = fast_tanh(zb.w + db.w);
    {
      int tn = t + 2; if (tn > L_ - 1) tn = L_ - 1;
      za = *(const float4*)&Zb[(size_t)tn * H_ + 4 * ln];
      zb = *(const float4*)&Zb[(size_t)tn * H_ + 256 + 4 * ln];
    }
    float p[V_];
#pragma unroll
    for (int v = 0; v < V_; ++v) {
      p[v] = w2a[v][0] * ha.x + w2a[v][1] * ha.y + w2a[v][2] * ha.z + w2a[v][3] * ha.w
           + w2b[v][0] * hb.x + w2b[v][1] * hb.y + w2b[v][2] * hb.z + w2b[v][3] * hb.w;
    }
#pragma unroll
    for (int v = 0; v < V_; ++v) sP[v * SP_PITCH + ln] = p[v];
    float lv = -INFINITY;
    if (ln < V_) {
      const float4* row = (const float4*)&sP[ln * SP_PITCH];
      float s0 = 0.f, s1 = 0.f, s2 = 0.f, s3 = 0.f;
#pragma unroll
      for (int i = 0; i < 16; ++i) {
        const float4 q = row[i];
        s0 += q.x; s1 += q.y; s2 += q.z; s3 += q.w;
      }
      lv = (s0 + s1) + (s2 + s3) + b2r;
    }
    float m = lv;
#pragma unroll
    for (int off = 32; off >= 1; off >>= 1) m = fmaxf(m, __shfl_xor(m, off, 64));
    const float e = __builtin_amdgcn_exp2f((lv - m) * LOG2E_F);
    float ssum = e;
#pragma unroll
    for (int off = 32; off >= 1; off >>= 1) ssum += __shfl_xor(ssum, off, 64);
    const float lse = __builtin_amdgcn_logf(ssum) * LN2_F;
    int idx = (lv == m) ? ln : 0x7fffffff;
#pragma unroll
    for (int off = 32; off >= 1; off >>= 1) idx = min(idx, __shfl_xor(idx, off, 64));

    const size_t rowBT = (size_t)b * L_ + t;
    if (ln < V_) {
      out_logits[rowBT * V_ + ln] = lv;
      out_probs[rowBT * V_ + ln] = lv - m - lse;
    }
    if (ln == 0) out_preds[rowBT] = (float)idx;
    if (ln < 16) {
      const float4 ev = *(const float4*)&sTab[idx * E_ + 4 * ln];
      *(float4*)&out_pemb[rowBT * E_ + 4 * ln] = ev;
    }
    pred = idx;
  };

  for (int t = 0; t < L_; t += 2) {
    step(t, za0, zb0);
    step(t + 1, za1, zb1);
  }
}

extern "C" void kernel_launch(void* const* d_in, const int* in_sizes, int n_in,
                              void* d_out, int out_size, void* d_ws, size_t ws_size,
                              hipStream_t stream) {
  const float* inputs = (const float*)d_in[0];
  const float* table  = (const float*)d_in[1];
  const float* W1     = (const float*)d_in[2];
  const float* b1     = (const float*)d_in[3];
  const float* W2     = (const float*)d_in[4];
  const float* b2     = (const float*)d_in[5];

  float* out = (float*)d_out;
  float* out_logits = out;                                  // [B,L,V]
  float* out_preds  = out_logits + (size_t)B_ * L_ * V_;    // [B,L]
  float* out_probs  = out_preds + (size_t)B_ * L_;          // [B,L,V]
  float* out_pemb   = out_probs + (size_t)B_ * L_ * V_;     // [B,L,E]

  float* DH = (float*)d_ws;                                 // 34 KB (reserve 64 KB)
  float* Z  = (float*)((char*)d_ws + 65536);                // 128 MB

  dh_kernel<<<1, 512, 0, stream>>>(W1, table, DH);
  dim3 g(65536 / GBM, H_ / GBN); // 512 x 4
  gemm_kernel<<<g, 256, 0, stream>>>(inputs, W1, b1, Z);
  seq_kernel<<<B_, 64, 0, stream>>>(Z, DH, W2, b2, table,
                                    out_logits, out_preds, out_probs, out_pemb);
}